// Round 16
// baseline (191.436 us; speedup 1.0000x reference)
//
#include <hip/hip_runtime.h>
#include <cmath>

#define B_ 2
#define N_ 4096
#define E_ 1024
#define D_ 128
#define H_ 8
#define CHUNK 64
#define NC_ (N_/CHUNK)   // 64
#define UW_ 3328         // padded u row width: v(1024) q(1024) lg(1024) G1(128) pad(128)

__device__ __forceinline__ float sigmoidf_(float x){ return 1.f/(1.f + __expf(-x)); }

__device__ __forceinline__ unsigned short f2bf(float f){
    unsigned u = __float_as_uint(f);
    u += 0x7FFFu + ((u >> 16) & 1u);      // round-to-nearest-even
    return (unsigned short)(u >> 16);
}
__device__ __forceinline__ float bf2f(unsigned short s){
    return __uint_as_float(((unsigned)s) << 16);
}
__device__ __forceinline__ unsigned short f2bf_fast(float f){
    __bf16 h = (__bf16)f;
    return __builtin_bit_cast(unsigned short, h);
}

typedef __attribute__((ext_vector_type(8))) __bf16 bf16x8;
typedef __attribute__((ext_vector_type(4))) float  f32x4;
typedef __attribute__((address_space(3))) unsigned int as3_u32;
typedef __attribute__((address_space(1))) unsigned int as1_u32;

__device__ __forceinline__ void gload_lds16(const void* g, void* l){
    __builtin_amdgcn_global_load_lds((as1_u32*)g, (as3_u32*)l, 16, 0, 0);
}

__device__ __forceinline__ bf16x8 ldsfrag256(const unsigned short* Lp, int row, int kg){
    return *reinterpret_cast<const bf16x8*>(&Lp[row*128 + ((kg ^ (row&7))<<3)]);
}
__device__ __forceinline__ bf16x8 ldsfrag128(const unsigned short* Lp, int row, int kg){
    return *reinterpret_cast<const bf16x8*>(&Lp[row*64 + ((kg ^ (row&7))<<3)]);
}
__device__ __forceinline__ bf16x8 u4_to_bf(uint4 u){
    return __builtin_bit_cast(bf16x8, u);
}

// ===========================================================================
// 256x256 8-phase deep-pipelined bf16 GEMM (verified round 15; parity+ at
// K=1024 per m248's T3-at-small-K result). Requires M%256==0, N%256==0,
// K%64==0, K/64 even >= 2, grid multiple of 8.
// ===========================================================================
template<bool OUT_BF16>
__global__ __launch_bounds__(512) void gemm_8ph(
    const unsigned short* __restrict__ Ag,
    const unsigned short* __restrict__ Bg,
    void* __restrict__ Cout, int M, int N, int K, int lda, int ldc)
{
    __shared__ unsigned short LDS8[65536];   // 128 KiB
    const int tid  = threadIdx.x;
    const int wave = tid >> 6;
    const int lane = tid & 63;
    const int l15 = lane & 15, l4 = lane >> 4;
    const int wm = wave >> 2, wn = wave & 3;

    const int gx = gridDim.x;                // N/256
    const int nwg = gx * gridDim.y;
    int bid = blockIdx.y*gx + blockIdx.x;
    bid = (bid & 7)*(nwg >> 3) + (bid >> 3);
    const int m0 = (bid / gx) * 256, n0 = (bid % gx) * 256;

    f32x4 acc[8][4];
#pragma unroll
    for (int i=0;i<8;i++)
#pragma unroll
        for (int j=0;j<4;j++)
#pragma unroll
            for (int q=0;q<4;q++) acc[i][j][q]=0.f;

    bf16x8 a[4][2], b[2][2];

    auto STAGE_A = [&](int kt, int buf, int h){
        unsigned short* dst = &LDS8[(buf*2+h)*8192];
        const int k0 = kt*64;
#pragma unroll
        for (int j=0;j<2;j++){
            const int R = j*64 + wave*8 + (lane>>3);
            const int trow = j*128 + h*64 + (R&63);
            gload_lds16(Ag + (size_t)(m0+trow)*lda + k0 + (((lane&7) ^ (R&7))<<3),
                        dst + (j*64 + wave*8)*64);
        }
    };
    auto STAGE_B = [&](int kt, int buf, int h){
        unsigned short* dst = &LDS8[32768 + (buf*2+h)*8192];
        const int k0 = kt*64;
#pragma unroll
        for (int j=0;j<2;j++){
            const int R = j*64 + wave*8 + (lane>>3);
            const int tcol = (R>>5)*64 + h*32 + (R&31);
            gload_lds16(Bg + (size_t)(n0+tcol)*K + k0 + (((lane&7) ^ (R&7))<<3),
                        dst + (j*64 + wave*8)*64);
        }
    };

#define RD_A(BUF, MQ) { _Pragma("unroll") for (int f_=0;f_<4;f_++) _Pragma("unroll") \
    for (int k_=0;k_<2;k_++) a[f_][k_] = ldsfrag128(&LDS8[((BUF)*2+(MQ))*8192], wm*64 + f_*16 + l15, k_*4 + l4); }
#define RD_B(BUF, NQ) { _Pragma("unroll") for (int f_=0;f_<2;f_++) _Pragma("unroll") \
    for (int k_=0;k_<2;k_++) b[f_][k_] = ldsfrag128(&LDS8[32768 + ((BUF)*2+(NQ))*8192], wn*32 + f_*16 + l15, k_*4 + l4); }
#define MMQ(MQ, NQ) { __builtin_amdgcn_s_setprio(1); _Pragma("unroll") \
    for (int k_=0;k_<2;k_++) _Pragma("unroll") for (int f_=0;f_<4;f_++) _Pragma("unroll") \
    for (int g_=0;g_<2;g_++) acc[(MQ)*4+f_][(NQ)*2+g_] = __builtin_amdgcn_mfma_f32_16x16x32_bf16( \
        a[f_][k_], b[g_][k_], acc[(MQ)*4+f_][(NQ)*2+g_], 0,0,0); __builtin_amdgcn_s_setprio(0); }
#define BAR1() { __builtin_amdgcn_s_barrier(); \
    asm volatile("s_waitcnt lgkmcnt(0)" ::: "memory"); __builtin_amdgcn_sched_barrier(0); }
#define BAR2() { __builtin_amdgcn_s_barrier(); __builtin_amdgcn_sched_barrier(0); }
#define VM6BAR() { asm volatile("s_waitcnt vmcnt(6)" ::: "memory"); \
    __builtin_amdgcn_s_barrier(); __builtin_amdgcn_sched_barrier(0); }

    STAGE_A(0,0,0); STAGE_B(0,0,0); STAGE_B(0,0,1); STAGE_A(0,0,1);
    STAGE_A(1,1,0); STAGE_B(1,1,1); STAGE_A(1,1,1);
    asm volatile("s_waitcnt vmcnt(0)" ::: "memory");
    BAR2();

    const int NT = K >> 6;
    for (int i=0; i<(NT>>1); ++i){
        const int t1 = 2*i+1;
        const int t2 = (2*i+2 < NT) ? 2*i+2 : 0;
        const int t3 = (2*i+3 < NT) ? 2*i+3 : 0;
        RD_A(0,0); RD_B(0,0); STAGE_B(t1, 1, 0);
        BAR1(); MMQ(0,0); BAR2();
        RD_B(0,1); STAGE_A(t2, 0, 0);
        BAR1(); MMQ(0,1); BAR2();
        RD_A(0,1); STAGE_B(t2, 0, 1);
        BAR1(); MMQ(1,1); BAR2();
        RD_B(0,0); STAGE_A(t2, 0, 1);
        BAR1(); MMQ(1,0); VM6BAR();
        RD_A(1,0); RD_B(1,0); STAGE_B(t2, 0, 0);
        BAR1(); MMQ(0,0); BAR2();
        RD_B(1,1); STAGE_A(t3, 1, 0);
        BAR1(); MMQ(0,1); BAR2();
        RD_A(1,1); STAGE_B(t3, 1, 1);
        BAR1(); MMQ(1,1); BAR2();
        RD_B(1,0); STAGE_A(t3, 1, 1);
        BAR1(); MMQ(1,0); VM6BAR();
    }
    asm volatile("s_waitcnt vmcnt(0)" ::: "memory");
#undef RD_A
#undef RD_B
#undef MMQ
#undef BAR1
#undef BAR2
#undef VM6BAR

    if (!OUT_BF16){
        float* C = (float*)Cout;
#pragma unroll
        for (int mq=0; mq<2; mq++)
#pragma unroll
            for (int f=0; f<4; f++)
#pragma unroll
                for (int nq=0; nq<2; nq++)
#pragma unroll
                    for (int g=0; g<2; g++)
#pragma unroll
                        for (int j=0;j<4;j++)
                            C[(size_t)(m0 + wm*128 + mq*64 + f*16 + l4*4 + j)*ldc
                              + n0 + wn*64 + nq*32 + g*16 + l15] = acc[mq*4+f][nq*2+g][j];
    } else {
        unsigned short* C = (unsigned short*)Cout;
#pragma unroll
        for (int mq=0; mq<2; mq++)
#pragma unroll
            for (int f=0; f<4; f++)
#pragma unroll
                for (int nq=0; nq<2; nq++)
#pragma unroll
                    for (int g=0; g<2; g++)
#pragma unroll
                        for (int j=0;j<4;j++)
                            C[(size_t)(m0 + wm*128 + mq*64 + f*16 + l4*4 + j)*ldc
                              + n0 + wn*64 + nq*32 + g*16 + l15] = f2bf(acc[mq*4+f][nq*2+g][j]);
    }
}

// ---------------------------------------------------------------------------
// 128x128 bf16 MFMA GEMM (m97 structure, proven) — small GEMMs.
// ---------------------------------------------------------------------------
template<bool OUT_BF16>
__global__ __launch_bounds__(256) void gemm_bf16(
    const unsigned short* __restrict__ A,
    const unsigned short* __restrict__ Bw,
    void* __restrict__ Cout, int M, int N, int K, int lda)
{
    __shared__ unsigned short As[128*64];
    __shared__ unsigned short Bs[128*64];
    const int tid  = threadIdx.x;
    const int wave = tid >> 6;
    const int lane = tid & 63;
    const int gx = gridDim.x;
    const int nwg = gx * gridDim.y;
    int bid = blockIdx.y*gx + blockIdx.x;
    bid = (bid & 7)*(nwg >> 3) + (bid >> 3);
    const int m0 = (bid / gx) * 128, n0 = (bid % gx) * 128;
    const int wr = (wave >> 1) * 64;
    const int wc = (wave & 1) * 64;
    const int l15 = lane & 15, l4 = lane >> 4;
    const int p = l15 & 7;

    f32x4 acc[4][4];
#pragma unroll
    for (int i=0;i<4;i++)
#pragma unroll
        for (int j=0;j<4;j++)
#pragma unroll
            for (int q=0;q<4;q++) acc[i][j][q]=0.f;

    const int srow = wave*32 + (lane>>3);
    const int sgrp = lane & 7;

    for (int k0=0; k0<K; k0+=64){
        if (k0) __syncthreads();
#pragma unroll
        for (int i=0;i<4;i++){
            const int r  = srow + 8*i;
            const int cg = sgrp ^ (r & 7);
            gload_lds16(A  + (size_t)(m0 + r)*lda + k0 + cg*8, &As[(wave*32 + 8*i)*64]);
            gload_lds16(Bw + (size_t)(n0 + r)*K   + k0 + cg*8, &Bs[(wave*32 + 8*i)*64]);
        }
        __syncthreads();
#pragma unroll
        for (int ks=0; ks<2; ks++){
            bf16x8 av[4], bv[4];
            const int tA = (((ks<<2) | l4) ^ p) << 3;
#pragma unroll
            for (int f=0; f<4; f++){
                const int rowA = wr + f*16 + l15;
                const int rowB = wc + f*16 + l15;
                av[f] = *reinterpret_cast<const bf16x8*>(&As[(rowA<<6) + tA]);
                bv[f] = *reinterpret_cast<const bf16x8*>(&Bs[(rowB<<6) + tA]);
            }
#pragma unroll
            for (int fm=0; fm<4; fm++)
#pragma unroll
                for (int fn=0; fn<4; fn++)
                    acc[fm][fn] = __builtin_amdgcn_mfma_f32_16x16x32_bf16(
                        av[fm], bv[fn], acc[fm][fn], 0, 0, 0);
        }
    }
    const int crow0 = m0 + wr + l4*4;
    const int ccol0 = n0 + wc + l15;
    if (!OUT_BF16){
        float* C = (float*)Cout;
#pragma unroll
        for (int fm=0; fm<4; fm++)
#pragma unroll
            for (int fn=0; fn<4; fn++)
#pragma unroll
                for (int j=0;j<4;j++)
                    C[(size_t)(crow0 + fm*16 + j)*N + ccol0 + fn*16] = acc[fm][fn][j];
    } else {
        unsigned short* C = (unsigned short*)Cout;
#pragma unroll
        for (int fm=0; fm<4; fm++)
#pragma unroll
            for (int fn=0; fn<4; fn++)
#pragma unroll
                for (int j=0;j<4;j++)
                    C[(size_t)(crow0 + fm*16 + j)*N + ccol0 + fn*16] = f2bf(acc[fm][fn][j]);
    }
}

// ---------------------------------------------------------------------------
// Merged f32 -> bf16 cast.
// ---------------------------------------------------------------------------
#define CQX 2097152   // x quads
#define WQ1 786432    // W_in quads
#define WQ3 32768     // W_g1 quads
#define WQ2 262144    // W_out quads
#define WQ4 32768     // W_g2 quads
__global__ __launch_bounds__(256) void cast_all(
    const float* __restrict__ x,
    const float* __restrict__ w1, const float* __restrict__ w3,
    const float* __restrict__ w2, const float* __restrict__ w4,
    unsigned short* __restrict__ xb, unsigned short* __restrict__ wcat,
    unsigned short* __restrict__ w2b, unsigned short* __restrict__ w4b)
{
    const int total = CQX+WQ1+WQ3+WQ2+WQ4;
    for (int i = blockIdx.x*256 + threadIdx.x; i < total; i += gridDim.x*256){
        const float* src; unsigned short* dst; int off;
        if (i < CQX){ src=x; dst=xb; off=i; }
        else if (i < CQX+WQ1){ src=w1; dst=wcat; off=i-CQX; }
        else if (i < CQX+WQ1+WQ3){ src=w3; dst=wcat+WQ1*4; off=i-CQX-WQ1; }
        else if (i < CQX+WQ1+WQ3+WQ2){ src=w2; dst=w2b; off=i-CQX-WQ1-WQ3; }
        else { src=w4; dst=w4b; off=i-CQX-WQ1-WQ3-WQ2; }
        const float4 v = reinterpret_cast<const float4*>(src)[off];
        ushort4 o;
        o.x = f2bf(v.x); o.y = f2bf(v.y); o.z = f2bf(v.z); o.w = f2bf(v.w);
        reinterpret_cast<ushort4*>(dst)[off] = o;
    }
}

// ---------------------------------------------------------------------------
// Prep v5 (stride UW_=3328) + G1 compaction (hh==0 blocks copy their 64 rows
// of ub2 cols 3072..3199 into dense G1c[8192][128]).
// ---------------------------------------------------------------------------
__global__ __launch_bounds__(512) void gla_prep(
    const unsigned short* __restrict__ u, float* __restrict__ EBC,
    unsigned short* __restrict__ QSb, unsigned short* __restrict__ KINb,
    unsigned short* __restrict__ KINtb, unsigned short* __restrict__ Vtb,
    unsigned short* __restrict__ G1c)
{
    __shared__ float tot[4*128];
    const int bid = blockIdx.x;               // (b*H+h)*NC + c
    const int c  = bid % NC_;
    const int hh = (bid / NC_) % H_;
    const int b  = bid / (NC_*H_);
    const int d  = threadIdx.x & 127;
    const int qd = threadIdx.x >> 7;
    const int t0 = qd*16;
    const size_t urow0 = ((size_t)b*N_ + (size_t)c*CHUNK)*UW_ + (size_t)hh*D_ + d;

    // G1 compaction: hh==0 blocks copy rows [b*N + c*64, +64), 16B/thread x2
    if (hh == 0){
        const size_t row0 = (size_t)b*N_ + (size_t)c*CHUNK;
#pragma unroll
        for (int i=0;i<2;i++){
            const int chunk = i*512 + threadIdx.x;     // < 1024 16B-chunks
            const int r = chunk >> 4, g8 = (chunk & 15)*8;
            *reinterpret_cast<uint4*>(&G1c[(row0 + r)*D_ + g8]) =
                *reinterpret_cast<const uint4*>(&u[(row0 + r)*UW_ + 3*E_ + g8]);
        }
    }

    float bl[16], qv[16], vv[16];
#pragma unroll
    for (int i=0;i<16;i++)
        bl[i] = bf2f(u[urow0 + (size_t)(t0+i)*UW_ + 2*E_]);
#pragma unroll
    for (int i=0;i<16;i++)
        qv[i] = bf2f(u[urow0 + (size_t)(t0+i)*UW_ + E_]);
#pragma unroll
    for (int i=0;i<16;i++)
        vv[i] = bf2f(u[urow0 + (size_t)(t0+i)*UW_]);

    float acc = 0.f;
#pragma unroll
    for (int i=0;i<16;i++){
        const float lg = bl[i];
        const float e  = __expf(-fabsf(lg));
        const float g  = fminf(lg, 0.f) - __logf(1.f + e);
        acc += g;
        bl[i] = acc;
    }
    tot[qd*128 + d] = acc;
    __syncthreads();
    const float s0 = tot[d], s1 = tot[128+d], s2 = tot[256+d], s3 = tot[384+d];
    const float off = (qd>0 ? s0 : 0.f) + (qd>1 ? s1 : 0.f) + (qd>2 ? s2 : 0.f);
    const float bcv = s0 + s1 + s2 + s3;
    const float ebc = __expf(bcv);
    if (threadIdx.x < 128) EBC[(size_t)bid*D_ + d] = ebc;

    unsigned kin_pk[8], v_pk[8];
    float prev = 0.f;
    const size_t obase = (size_t)bid*CHUNK*D_;
#pragma unroll
    for (int i=0;i<16;i++){
        const int t = t0 + i;
        const float Bl = bl[i];
        const float g  = Bl - prev;  prev = Bl;
        const float Bc = Bl + off;
        const float kk = 1.f - __expf(g);
        const float eB = __expf(Bc);
        const float q  = qv[i];
        const float es = __expf(-q);
        const float silu = q * __builtin_amdgcn_rcpf(1.f + es);
        const float qs  = silu * eB;
        const float kin = kk * __builtin_amdgcn_rcpf(eB);
        QSb [obase + (size_t)t*D_ + d] = f2bf_fast(qs);
        KINb[obase + (size_t)t*D_ + d] = f2bf_fast(kin);
        const unsigned kb = f2bf_fast(kin * ebc);
        const unsigned vb = f2bf_fast(vv[i]);
        if (i & 1){ kin_pk[i>>1] |= kb<<16; v_pk[i>>1] |= vb<<16; }
        else      { kin_pk[i>>1]  = kb;     v_pk[i>>1]  = vb;     }
    }
    const size_t tbase = (size_t)bid*D_*CHUNK + (size_t)d*CHUNK + t0;
#pragma unroll
    for (int j=0;j<2;j++){
        uint4 kq, vq;
        kq.x=kin_pk[4*j]; kq.y=kin_pk[4*j+1]; kq.z=kin_pk[4*j+2]; kq.w=kin_pk[4*j+3];
        vq.x=v_pk[4*j];   vq.y=v_pk[4*j+1];   vq.z=v_pk[4*j+2];   vq.w=v_pk[4*j+3];
        *reinterpret_cast<uint4*>(&KINtb[tbase + j*8]) = kq;
        *reinterpret_cast<uint4*>(&Vtb  [tbase + j*8]) = vq;
    }
}

// ---------------------------------------------------------------------------
__global__ __launch_bounds__(256) void gla_chunk_mm(
    const unsigned short* __restrict__ Vtb,
    const unsigned short* __restrict__ KINtb,
    unsigned short* __restrict__ McTb)
{
    __shared__ unsigned short As[128*64];
    __shared__ unsigned short Bs[128*64];
    const int bid = blockIdx.x;
    const int tid = threadIdx.x;
    const int w = tid >> 6, lane = tid & 63;
    const int l15 = lane & 15, l4 = lane >> 4;
    const int wr = (w >> 1) * 64, wc = (w & 1) * 64;
    const unsigned short* A  = Vtb   + (size_t)bid*128*64;
    const unsigned short* Bp = KINtb + (size_t)bid*128*64;

    f32x4 acc[4][4];
#pragma unroll
    for (int i=0;i<4;i++)
#pragma unroll
        for (int j=0;j<4;j++)
#pragma unroll
            for (int q=0;q<4;q++) acc[i][j][q]=0.f;

#pragma unroll
    for (int i=0;i<4;i++){
        const int r  = w*32 + i*8 + (lane>>3);
        const int gs = (lane&7) ^ (r&7);
        gload_lds16(A  + (size_t)r*64 + gs*8, &As[(w*32+i*8)*64]);
        gload_lds16(Bp + (size_t)r*64 + gs*8, &Bs[(w*32+i*8)*64]);
    }
    __syncthreads();
#pragma unroll
    for (int ks=0; ks<2; ks++){
        bf16x8 av[4], bv[4];
#pragma unroll
        for (int f=0; f<4; f++){
            av[f] = ldsfrag128(As, wr + f*16 + l15, ks*4 + l4);
            bv[f] = ldsfrag128(Bs, wc + f*16 + l15, ks*4 + l4);
        }
#pragma unroll
        for (int fm=0; fm<4; fm++)
#pragma unroll
            for (int fn=0; fn<4; fn++)
                acc[fm][fn] = __builtin_amdgcn_mfma_f32_16x16x32_bf16(
                    av[fm], bv[fn], acc[fm][fn], 0, 0, 0);
    }
    unsigned short* C = McTb + (size_t)bid*128*128;
#pragma unroll
    for (int fm=0; fm<4; fm++)
#pragma unroll
        for (int fn=0; fn<4; fn++)
#pragma unroll
            for (int j=0;j<4;j++)
                C[(size_t)(wr + fm*16 + l4*4 + j)*128 + wc + fn*16 + l15] = f2bf(acc[fm][fn][j]);
}

// ---------------------------------------------------------------------------
// Inter-chunk scan, vectorized x4 (r12-verified).
// ---------------------------------------------------------------------------
__global__ __launch_bounds__(256) void gla_scan_chunks(
    const unsigned short* __restrict__ McTb, const float* __restrict__ EBC,
    unsigned short* __restrict__ Sb16)
{
    const int F4 = blockIdx.x*256 + threadIdx.x;   // < B*H*D*D/4 = 65536
    const int e4 = F4 << 2;
    const int bh = e4 >> 14;
    const int rem = e4 & 16383;
    const int d0 = rem & 127;
    float S0=0.f, S1=0.f, S2=0.f, S3=0.f;
    for (int c=0;c<NC_;c++){
        const size_t idx = (((size_t)bh*NC_ + c) << 14) + rem;
        const ushort4 m4 = *reinterpret_cast<const ushort4*>(&McTb[idx]);
        const float4 dec = *reinterpret_cast<const float4*>(
            &EBC[(((size_t)bh*NC_ + c) << 7) + d0]);
        ushort4 s4;
        s4.x = f2bf(S0); s4.y = f2bf(S1); s4.z = f2bf(S2); s4.w = f2bf(S3);
        *reinterpret_cast<ushort4*>(&Sb16[idx]) = s4;
        S0 = dec.x*S0 + bf2f(m4.x);
        S1 = dec.y*S1 + bf2f(m4.y);
        S2 = dec.z*S2 + bf2f(m4.z);
        S3 = dec.w*S3 + bf2f(m4.w);
    }
}

// ---------------------------------------------------------------------------
// Output (r11 proven): QS in LDS, KIN/Vt/S direct-from-global, G2b gate,
// bf16 Opre.
// ---------------------------------------------------------------------------
__global__ __launch_bounds__(256) void gla_output(
    const unsigned short* __restrict__ QSb,
    const unsigned short* __restrict__ KINb,
    const unsigned short* __restrict__ Vtb,
    const unsigned short* __restrict__ Sb,
    const unsigned short* __restrict__ G2b,
    unsigned short* __restrict__ Opre)
{
    __shared__ unsigned short QS_l[64*128];   // 16 KB
    __shared__ unsigned short A_l [64*64];    //  8 KB
    const int bid = blockIdx.x;
    const int c = bid % NC_;
    const int h = (bid / NC_) % H_;
    const int b = bid / (NC_*H_);
    const int tid = threadIdx.x;
    const int w = tid >> 6, lane = tid & 63;
    const int l15 = lane & 15, l4 = lane >> 4;

    const unsigned short* qb = QSb + (size_t)bid*64*128;
    const unsigned short* kb = KINb + (size_t)bid*64*128;
    const unsigned short* vb = Vtb + (size_t)bid*128*64;
    const unsigned short* sb = Sb  + (size_t)bid*128*128;

#pragma unroll
    for (int i=0;i<4;i++){
        const int r  = w*16 + i*4 + (lane>>4);
        const int gs = (lane&15) ^ (r&7);
        gload_lds16(qb + (size_t)r*128 + gs*8, &QS_l[(w*16+i*4)*128]);
    }
    uint4 kinr[4];
    {
        const int srow = w*16 + l15;
#pragma unroll
        for (int ks=0; ks<4; ks++)
            kinr[ks] = *reinterpret_cast<const uint4*>(kb + (size_t)srow*128 + (ks*4 + l4)*8);
    }
    __syncthreads();

    uint4 vtr[2][2], sr[2][4];
#pragma unroll
    for (int fe=0; fe<2; fe++){
        const int row = w*32 + fe*16 + l15;
#pragma unroll
        for (int ks=0; ks<2; ks++)
            vtr[fe][ks] = *reinterpret_cast<const uint4*>(vb + (size_t)row*64 + (ks*4 + l4)*8);
#pragma unroll
        for (int ks=0; ks<4; ks++)
            sr[fe][ks]  = *reinterpret_cast<const uint4*>(sb + (size_t)row*128 + (ks*4 + l4)*8);
    }

    f32x4 accA[4];
#pragma unroll
    for (int i=0;i<4;i++)
#pragma unroll
        for (int q=0;q<4;q++) accA[i][q]=0.f;
#pragma unroll
    for (int ks=0; ks<4; ks++){
        const bf16x8 bv = u4_to_bf(kinr[ks]);
#pragma unroll
        for (int ft=0; ft<4; ft++){
            const bf16x8 av = ldsfrag256(QS_l, ft*16 + l15, ks*4 + l4);
            accA[ft] = __builtin_amdgcn_mfma_f32_16x16x32_bf16(av, bv, accA[ft], 0,0,0);
        }
    }
#pragma unroll
    for (int ft=0; ft<4; ft++)
#pragma unroll
        for (int j=0;j<4;j++){
            const int t = ft*16 + l4*4 + j;
            const int s = w*16 + l15;
            const float vA = (t >= s) ? accA[ft][j] : 0.f;
            A_l[t*64 + (((s>>3) ^ (t&7))<<3) + (s&7)] = f2bf(vA);
        }
    __syncthreads();

    f32x4 acc[4][2];
#pragma unroll
    for (int i=0;i<4;i++)
#pragma unroll
        for (int j=0;j<2;j++)
#pragma unroll
            for (int q=0;q<4;q++) acc[i][j][q]=0.f;
#pragma unroll
    for (int ks=0; ks<2; ks++){
        const bf16x8 b0 = u4_to_bf(vtr[0][ks]);
        const bf16x8 b1 = u4_to_bf(vtr[1][ks]);
#pragma unroll
        for (int ft=0; ft<4; ft++){
            const bf16x8 av = ldsfrag128(A_l, ft*16 + l15, ks*4 + l4);
            acc[ft][0] = __builtin_amdgcn_mfma_f32_16x16x32_bf16(av, b0, acc[ft][0], 0,0,0);
            acc[ft][1] = __builtin_amdgcn_mfma_f32_16x16x32_bf16(av, b1, acc[ft][1], 0,0,0);
        }
    }
#pragma unroll
    for (int ks=0; ks<4; ks++){
        const bf16x8 b0 = u4_to_bf(sr[0][ks]);
        const bf16x8 b1 = u4_to_bf(sr[1][ks]);
#pragma unroll
        for (int ft=0; ft<4; ft++){
            const bf16x8 av = ldsfrag256(QS_l, ft*16 + l15, ks*4 + l4);
            acc[ft][0] = __builtin_amdgcn_mfma_f32_16x16x32_bf16(av, b0, acc[ft][0], 0,0,0);
            acc[ft][1] = __builtin_amdgcn_mfma_f32_16x16x32_bf16(av, b1, acc[ft][1], 0,0,0);
        }
    }
    const size_t rowbase = (size_t)b*N_ + (size_t)c*CHUNK;
#pragma unroll
    for (int ft=0; ft<4; ft++)
#pragma unroll
        for (int fe=0; fe<2; fe++)
#pragma unroll
            for (int j=0;j<4;j++){
                const int t = ft*16 + l4*4 + j;
                const int e = w*32 + fe*16 + l15;
                const size_t idx = (rowbase + t)*E_ + h*D_ + e;
                const float g = sigmoidf_(bf2f(G2b[idx]));
                Opre[idx] = f2bf(acc[ft][fe][j] * g);
            }
}

// ---------------------------------------------------------------------------
__global__ __launch_bounds__(256) void ln_bf16(
    const unsigned short* __restrict__ O, const float* __restrict__ lnw,
    unsigned short* __restrict__ Ob)
{
    const int row = blockIdx.x;
    const int tid = threadIdx.x;
    const size_t off = (size_t)row*E_ + tid*4;
    const ushort4 ov = *reinterpret_cast<const ushort4*>(&O[off]);
    float4 o;
    o.x = bf2f(ov.x); o.y = bf2f(ov.y); o.z = bf2f(ov.z); o.w = bf2f(ov.w);
    float s1 = o.x+o.y+o.z+o.w;
    float s2 = o.x*o.x + o.y*o.y + o.z*o.z + o.w*o.w;
#pragma unroll
    for (int sh=32; sh>0; sh>>=1){
        s1 += __shfl_down(s1, sh);
        s2 += __shfl_down(s2, sh);
    }
    __shared__ float r1[4], r2[4];
    const int wid = tid >> 6;
    if ((tid & 63)==0){ r1[wid]=s1; r2[wid]=s2; }
    __syncthreads();
    s1 = r1[0]+r1[1]+r1[2]+r1[3];
    s2 = r2[0]+r2[1]+r2[2]+r2[3];
    const float mean = s1 * (1.f/E_);
    const float var  = s2 * (1.f/E_) - mean*mean;
    const float rs   = rsqrtf(var + 1e-5f);
    const float4 w = *reinterpret_cast<const float4*>(&lnw[tid*4]);
    ushort4 r;
    r.x = f2bf((o.x-mean)*rs*w.x); r.y = f2bf((o.y-mean)*rs*w.y);
    r.z = f2bf((o.z-mean)*rs*w.z); r.w = f2bf((o.w-mean)*rs*w.w);
    *reinterpret_cast<ushort4*>(&Ob[off]) = r;
}

// ---------------------------------------------------------------------------
extern "C" void kernel_launch(void* const* d_in, const int* in_sizes, int n_in,
                              void* d_out, int out_size, void* d_ws, size_t ws_size,
                              hipStream_t stream)
{
    const float* x     = (const float*)d_in[0];
    const float* W_in  = (const float*)d_in[1];
    const float* W_out = (const float*)d_in[2];
    const float* W_g1  = (const float*)d_in[3];
    const float* W_g2  = (const float*)d_in[4];
    const float* lnw   = (const float*)d_in[5];
    float* out = (float*)d_out;
    char* ws = (char*)d_ws;

    // workspace layout (bytes); total 217,317,376 (< proven-safe 246 MB)
    unsigned short* ub2    = (unsigned short*)(ws);             //  54,525,952 [B,N,3328] (dead after prep)
    unsigned short* McTb   = (unsigned short*)(ws);             //  33,554,432 overlay on dead ub2
    unsigned short* QSb    = (unsigned short*)(ws + 54525952);  //  16,777,216
    unsigned short* KINb   = (unsigned short*)(ws + 71303168);  //  16,777,216
    unsigned short* KINtb  = (unsigned short*)(ws + 88080384);  //  16,777,216
    unsigned short* Vtb    = (unsigned short*)(ws + 104857600); //  16,777,216
    unsigned short* Sb16   = (unsigned short*)(ws + 121634816); //  33,554,432
    float*          EBC    = (float*)(ws + 155189248);          //     524,288
    unsigned short* Opre   = (unsigned short*)(ws + 155713536); //  16,777,216
    unsigned short* ObF    = (unsigned short*)(ws + 172490752); //  16,777,216
    unsigned short* xb     = (unsigned short*)(ws + 189267968); //  16,777,216 (dead after step 1)
    unsigned short* G2b    = (unsigned short*)(ws + 189267968); //  16,777,216 overlay on dead xb
    unsigned short* Wcatb  = (unsigned short*)(ws + 206045184); //   6,815,744 [3328,1024] (rows 3200+ garbage)
    unsigned short* W_outb = (unsigned short*)(ws + 212860928); //   2,097,152
    unsigned short* W_g2b  = (unsigned short*)(ws + 214958080); //     262,144
    unsigned short* G1c    = (unsigned short*)(ws + 215220224); //   2,097,152 [8192,128]

    const int M = B_*N_;     // 8192
    dim3 blk(256);

    // 0) merged casts
    cast_all<<<2048, blk, 0, stream>>>(x, W_in, W_g1, W_out, W_g2,
                                       xb, Wcatb, W_outb, W_g2b);

    // 1) u2 = x @ [W_in; W_g1; pad]^T  — 8-phase 256^2
    gemm_8ph<true><<<dim3(UW_/256, M/256), dim3(512), 0, stream>>>(
        xb, Wcatb, ub2, M, UW_, E_, E_, UW_);
    // 2) prep (stride 3328) + G1 compaction -> G1c
    gla_prep<<<dim3(B_*H_*NC_), dim3(512), 0, stream>>>(ub2, EBC, QSb, KINb, KINtb, Vtb, G1c);
    // 3) G2 = G1c @ W_g2^T  (dense lda=128) — m97
    gemm_bf16<true><<<dim3(E_/128, M/128), blk, 0, stream>>>(
        G1c, W_g2b, G2b, M, E_, D_, D_);
    // 4) per-chunk summaries (McTb overlays dead ub2)
    gla_chunk_mm<<<dim3(B_*H_*NC_), blk, 0, stream>>>(Vtb, KINtb, McTb);
    // 5) inter-chunk scan (vectorized x4)
    gla_scan_chunks<<<dim3((B_*H_*D_*D_)/1024), blk, 0, stream>>>(McTb, EBC, Sb16);
    // 6) per-chunk outputs + gate -> bf16 Opre
    gla_output<<<dim3(B_*H_*NC_), blk, 0, stream>>>(QSb, KINb, Vtb, Sb16, G2b, Opre);
    // 7) layernorm -> bf16
    ln_bf16<<<dim3(M), blk, 0, stream>>>(Opre, lnw, ObF);
    // 8) out = LN(o) @ W_out^T — m97
    gemm_bf16<false><<<dim3(E_/128, M/128), blk, 0, stream>>>(
        ObF, W_outb, out, M, E_, E_, E_);
}

// Round 17
// 182.458 us; speedup vs baseline: 1.0492x; 1.0492x over previous
//
#include <hip/hip_runtime.h>
#include <cmath>

#define B_ 2
#define N_ 4096
#define E_ 1024
#define D_ 128
#define H_ 8
#define CHUNK 64
#define NC_ (N_/CHUNK)   // 64
#define UW_ 3328         // padded u row width: v(1024) q(1024) lg(1024) G1(128) pad(128)

__device__ __forceinline__ float sigmoidf_(float x){ return 1.f/(1.f + __expf(-x)); }

__device__ __forceinline__ unsigned short f2bf(float f){
    unsigned u = __float_as_uint(f);
    u += 0x7FFFu + ((u >> 16) & 1u);      // round-to-nearest-even
    return (unsigned short)(u >> 16);
}
__device__ __forceinline__ float bf2f(unsigned short s){
    return __uint_as_float(((unsigned)s) << 16);
}
__device__ __forceinline__ unsigned short f2bf_fast(float f){
    __bf16 h = (__bf16)f;
    return __builtin_bit_cast(unsigned short, h);
}

typedef __attribute__((ext_vector_type(8))) __bf16 bf16x8;
typedef __attribute__((ext_vector_type(4))) float  f32x4;
typedef __attribute__((address_space(3))) unsigned int as3_u32;
typedef __attribute__((address_space(1))) unsigned int as1_u32;

__device__ __forceinline__ void gload_lds16(const void* g, void* l){
    __builtin_amdgcn_global_load_lds((as1_u32*)g, (as3_u32*)l, 16, 0, 0);
}

__device__ __forceinline__ bf16x8 ldsfrag256(const unsigned short* Lp, int row, int kg){
    return *reinterpret_cast<const bf16x8*>(&Lp[row*128 + ((kg ^ (row&7))<<3)]);
}
__device__ __forceinline__ bf16x8 ldsfrag128(const unsigned short* Lp, int row, int kg){
    return *reinterpret_cast<const bf16x8*>(&Lp[row*64 + ((kg ^ (row&7))<<3)]);
}
__device__ __forceinline__ bf16x8 u4_to_bf(uint4 u){
    return __builtin_bit_cast(bf16x8, u);
}

// ===========================================================================
// 256x256 8-phase deep-pipelined bf16 GEMM (verified rounds 15/16).
// ===========================================================================
template<bool OUT_BF16>
__global__ __launch_bounds__(512) void gemm_8ph(
    const unsigned short* __restrict__ Ag,
    const unsigned short* __restrict__ Bg,
    void* __restrict__ Cout, int M, int N, int K, int lda, int ldc)
{
    __shared__ unsigned short LDS8[65536];   // 128 KiB
    const int tid  = threadIdx.x;
    const int wave = tid >> 6;
    const int lane = tid & 63;
    const int l15 = lane & 15, l4 = lane >> 4;
    const int wm = wave >> 2, wn = wave & 3;

    const int gx = gridDim.x;                // N/256
    const int nwg = gx * gridDim.y;
    int bid = blockIdx.y*gx + blockIdx.x;
    bid = (bid & 7)*(nwg >> 3) + (bid >> 3);
    const int m0 = (bid / gx) * 256, n0 = (bid % gx) * 256;

    f32x4 acc[8][4];
#pragma unroll
    for (int i=0;i<8;i++)
#pragma unroll
        for (int j=0;j<4;j++)
#pragma unroll
            for (int q=0;q<4;q++) acc[i][j][q]=0.f;

    bf16x8 a[4][2], b[2][2];

    auto STAGE_A = [&](int kt, int buf, int h){
        unsigned short* dst = &LDS8[(buf*2+h)*8192];
        const int k0 = kt*64;
#pragma unroll
        for (int j=0;j<2;j++){
            const int R = j*64 + wave*8 + (lane>>3);
            const int trow = j*128 + h*64 + (R&63);
            gload_lds16(Ag + (size_t)(m0+trow)*lda + k0 + (((lane&7) ^ (R&7))<<3),
                        dst + (j*64 + wave*8)*64);
        }
    };
    auto STAGE_B = [&](int kt, int buf, int h){
        unsigned short* dst = &LDS8[32768 + (buf*2+h)*8192];
        const int k0 = kt*64;
#pragma unroll
        for (int j=0;j<2;j++){
            const int R = j*64 + wave*8 + (lane>>3);
            const int tcol = (R>>5)*64 + h*32 + (R&31);
            gload_lds16(Bg + (size_t)(n0+tcol)*K + k0 + (((lane&7) ^ (R&7))<<3),
                        dst + (j*64 + wave*8)*64);
        }
    };

#define RD_A(BUF, MQ) { _Pragma("unroll") for (int f_=0;f_<4;f_++) _Pragma("unroll") \
    for (int k_=0;k_<2;k_++) a[f_][k_] = ldsfrag128(&LDS8[((BUF)*2+(MQ))*8192], wm*64 + f_*16 + l15, k_*4 + l4); }
#define RD_B(BUF, NQ) { _Pragma("unroll") for (int f_=0;f_<2;f_++) _Pragma("unroll") \
    for (int k_=0;k_<2;k_++) b[f_][k_] = ldsfrag128(&LDS8[32768 + ((BUF)*2+(NQ))*8192], wn*32 + f_*16 + l15, k_*4 + l4); }
#define MMQ(MQ, NQ) { __builtin_amdgcn_s_setprio(1); _Pragma("unroll") \
    for (int k_=0;k_<2;k_++) _Pragma("unroll") for (int f_=0;f_<4;f_++) _Pragma("unroll") \
    for (int g_=0;g_<2;g_++) acc[(MQ)*4+f_][(NQ)*2+g_] = __builtin_amdgcn_mfma_f32_16x16x32_bf16( \
        a[f_][k_], b[g_][k_], acc[(MQ)*4+f_][(NQ)*2+g_], 0,0,0); __builtin_amdgcn_s_setprio(0); }
#define BAR1() { __builtin_amdgcn_s_barrier(); \
    asm volatile("s_waitcnt lgkmcnt(0)" ::: "memory"); __builtin_amdgcn_sched_barrier(0); }
#define BAR2() { __builtin_amdgcn_s_barrier(); __builtin_amdgcn_sched_barrier(0); }
#define VM6BAR() { asm volatile("s_waitcnt vmcnt(6)" ::: "memory"); \
    __builtin_amdgcn_s_barrier(); __builtin_amdgcn_sched_barrier(0); }

    STAGE_A(0,0,0); STAGE_B(0,0,0); STAGE_B(0,0,1); STAGE_A(0,0,1);
    STAGE_A(1,1,0); STAGE_B(1,1,1); STAGE_A(1,1,1);
    asm volatile("s_waitcnt vmcnt(0)" ::: "memory");
    BAR2();

    const int NT = K >> 6;
    for (int i=0; i<(NT>>1); ++i){
        const int t1 = 2*i+1;
        const int t2 = (2*i+2 < NT) ? 2*i+2 : 0;
        const int t3 = (2*i+3 < NT) ? 2*i+3 : 0;
        RD_A(0,0); RD_B(0,0); STAGE_B(t1, 1, 0);
        BAR1(); MMQ(0,0); BAR2();
        RD_B(0,1); STAGE_A(t2, 0, 0);
        BAR1(); MMQ(0,1); BAR2();
        RD_A(0,1); STAGE_B(t2, 0, 1);
        BAR1(); MMQ(1,1); BAR2();
        RD_B(0,0); STAGE_A(t2, 0, 1);
        BAR1(); MMQ(1,0); VM6BAR();
        RD_A(1,0); RD_B(1,0); STAGE_B(t2, 0, 0);
        BAR1(); MMQ(0,0); BAR2();
        RD_B(1,1); STAGE_A(t3, 1, 0);
        BAR1(); MMQ(0,1); BAR2();
        RD_A(1,1); STAGE_B(t3, 1, 1);
        BAR1(); MMQ(1,1); BAR2();
        RD_B(1,0); STAGE_A(t3, 1, 1);
        BAR1(); MMQ(1,0); VM6BAR();
    }
    asm volatile("s_waitcnt vmcnt(0)" ::: "memory");
#undef RD_A
#undef RD_B
#undef MMQ
#undef BAR1
#undef BAR2
#undef VM6BAR

    if (!OUT_BF16){
        float* C = (float*)Cout;
#pragma unroll
        for (int mq=0; mq<2; mq++)
#pragma unroll
            for (int f=0; f<4; f++)
#pragma unroll
                for (int nq=0; nq<2; nq++)
#pragma unroll
                    for (int g=0; g<2; g++)
#pragma unroll
                        for (int j=0;j<4;j++)
                            C[(size_t)(m0 + wm*128 + mq*64 + f*16 + l4*4 + j)*ldc
                              + n0 + wn*64 + nq*32 + g*16 + l15] = acc[mq*4+f][nq*2+g][j];
    } else {
        unsigned short* C = (unsigned short*)Cout;
#pragma unroll
        for (int mq=0; mq<2; mq++)
#pragma unroll
            for (int f=0; f<4; f++)
#pragma unroll
                for (int nq=0; nq<2; nq++)
#pragma unroll
                    for (int g=0; g<2; g++)
#pragma unroll
                        for (int j=0;j<4;j++)
                            C[(size_t)(m0 + wm*128 + mq*64 + f*16 + l4*4 + j)*ldc
                              + n0 + wn*64 + nq*32 + g*16 + l15] = f2bf(acc[mq*4+f][nq*2+g][j]);
    }
}

// ---------------------------------------------------------------------------
// 128x128 bf16 MFMA GEMM (m97 structure, proven) — small GEMMs.
// ---------------------------------------------------------------------------
template<bool OUT_BF16>
__global__ __launch_bounds__(256) void gemm_bf16(
    const unsigned short* __restrict__ A,
    const unsigned short* __restrict__ Bw,
    void* __restrict__ Cout, int M, int N, int K, int lda)
{
    __shared__ unsigned short As[128*64];
    __shared__ unsigned short Bs[128*64];
    const int tid  = threadIdx.x;
    const int wave = tid >> 6;
    const int lane = tid & 63;
    const int gx = gridDim.x;
    const int nwg = gx * gridDim.y;
    int bid = blockIdx.y*gx + blockIdx.x;
    bid = (bid & 7)*(nwg >> 3) + (bid >> 3);
    const int m0 = (bid / gx) * 128, n0 = (bid % gx) * 128;
    const int wr = (wave >> 1) * 64;
    const int wc = (wave & 1) * 64;
    const int l15 = lane & 15, l4 = lane >> 4;
    const int p = l15 & 7;

    f32x4 acc[4][4];
#pragma unroll
    for (int i=0;i<4;i++)
#pragma unroll
        for (int j=0;j<4;j++)
#pragma unroll
            for (int q=0;q<4;q++) acc[i][j][q]=0.f;

    const int srow = wave*32 + (lane>>3);
    const int sgrp = lane & 7;

    for (int k0=0; k0<K; k0+=64){
        if (k0) __syncthreads();
#pragma unroll
        for (int i=0;i<4;i++){
            const int r  = srow + 8*i;
            const int cg = sgrp ^ (r & 7);
            gload_lds16(A  + (size_t)(m0 + r)*lda + k0 + cg*8, &As[(wave*32 + 8*i)*64]);
            gload_lds16(Bw + (size_t)(n0 + r)*K   + k0 + cg*8, &Bs[(wave*32 + 8*i)*64]);
        }
        __syncthreads();
#pragma unroll
        for (int ks=0; ks<2; ks++){
            bf16x8 av[4], bv[4];
            const int tA = (((ks<<2) | l4) ^ p) << 3;
#pragma unroll
            for (int f=0; f<4; f++){
                const int rowA = wr + f*16 + l15;
                const int rowB = wc + f*16 + l15;
                av[f] = *reinterpret_cast<const bf16x8*>(&As[(rowA<<6) + tA]);
                bv[f] = *reinterpret_cast<const bf16x8*>(&Bs[(rowB<<6) + tA]);
            }
#pragma unroll
            for (int fm=0; fm<4; fm++)
#pragma unroll
                for (int fn=0; fn<4; fn++)
                    acc[fm][fn] = __builtin_amdgcn_mfma_f32_16x16x32_bf16(
                        av[fm], bv[fn], acc[fm][fn], 0, 0, 0);
        }
    }
    const int crow0 = m0 + wr + l4*4;
    const int ccol0 = n0 + wc + l15;
    if (!OUT_BF16){
        float* C = (float*)Cout;
#pragma unroll
        for (int fm=0; fm<4; fm++)
#pragma unroll
            for (int fn=0; fn<4; fn++)
#pragma unroll
                for (int j=0;j<4;j++)
                    C[(size_t)(crow0 + fm*16 + j)*N + ccol0 + fn*16] = acc[fm][fn][j];
    } else {
        unsigned short* C = (unsigned short*)Cout;
#pragma unroll
        for (int fm=0; fm<4; fm++)
#pragma unroll
            for (int fn=0; fn<4; fn++)
#pragma unroll
                for (int j=0;j<4;j++)
                    C[(size_t)(crow0 + fm*16 + j)*N + ccol0 + fn*16] = f2bf(acc[fm][fn][j]);
    }
}

// ---------------------------------------------------------------------------
// Merged f32 -> bf16 cast.
// ---------------------------------------------------------------------------
#define CQX 2097152   // x quads
#define WQ1 786432    // W_in quads
#define WQ3 32768     // W_g1 quads
#define WQ2 262144    // W_out quads
#define WQ4 32768     // W_g2 quads
__global__ __launch_bounds__(256) void cast_all(
    const float* __restrict__ x,
    const float* __restrict__ w1, const float* __restrict__ w3,
    const float* __restrict__ w2, const float* __restrict__ w4,
    unsigned short* __restrict__ xb, unsigned short* __restrict__ wcat,
    unsigned short* __restrict__ w2b, unsigned short* __restrict__ w4b)
{
    const int total = CQX+WQ1+WQ3+WQ2+WQ4;
    for (int i = blockIdx.x*256 + threadIdx.x; i < total; i += gridDim.x*256){
        const float* src; unsigned short* dst; int off;
        if (i < CQX){ src=x; dst=xb; off=i; }
        else if (i < CQX+WQ1){ src=w1; dst=wcat; off=i-CQX; }
        else if (i < CQX+WQ1+WQ3){ src=w3; dst=wcat+WQ1*4; off=i-CQX-WQ1; }
        else if (i < CQX+WQ1+WQ3+WQ2){ src=w2; dst=w2b; off=i-CQX-WQ1-WQ3; }
        else { src=w4; dst=w4b; off=i-CQX-WQ1-WQ3-WQ2; }
        const float4 v = reinterpret_cast<const float4*>(src)[off];
        ushort4 o;
        o.x = f2bf(v.x); o.y = f2bf(v.y); o.z = f2bf(v.z); o.w = f2bf(v.w);
        reinterpret_cast<ushort4*>(dst)[off] = o;
    }
}

// ---------------------------------------------------------------------------
// Prep v6 (stride UW_=3328) + G1 compaction + FUSED chunk-summary MFMA:
// transposed KIN*e^{BC} and V tiles go to LDS (swizzled), then the block's
// 8 waves compute McT[e][d] = sum_s Vt[e,s]*KINt[d,s] directly (KINtb and
// the separate gla_chunk_mm kernel are eliminated).
// ---------------------------------------------------------------------------
__global__ __launch_bounds__(512) void gla_prep(
    const unsigned short* __restrict__ u, float* __restrict__ EBC,
    unsigned short* __restrict__ QSb, unsigned short* __restrict__ KINb,
    unsigned short* __restrict__ Vtb, unsigned short* __restrict__ McTb,
    unsigned short* __restrict__ G1c)
{
    __shared__ float tot[4*128];
    __shared__ unsigned short Vt_l[128*64];   // 16 KB
    __shared__ unsigned short Kt_l[128*64];   // 16 KB
    const int bid = blockIdx.x;               // (b*H+h)*NC + c
    const int c  = bid % NC_;
    const int hh = (bid / NC_) % H_;
    const int b  = bid / (NC_*H_);
    const int d  = threadIdx.x & 127;
    const int qd = threadIdx.x >> 7;
    const int t0 = qd*16;
    const size_t urow0 = ((size_t)b*N_ + (size_t)c*CHUNK)*UW_ + (size_t)hh*D_ + d;

    // G1 compaction: hh==0 blocks copy rows [b*N + c*64, +64)
    if (hh == 0){
        const size_t row0 = (size_t)b*N_ + (size_t)c*CHUNK;
#pragma unroll
        for (int i=0;i<2;i++){
            const int chunk = i*512 + threadIdx.x;     // < 1024 16B-chunks
            const int r = chunk >> 4, g8 = (chunk & 15)*8;
            *reinterpret_cast<uint4*>(&G1c[(row0 + r)*D_ + g8]) =
                *reinterpret_cast<const uint4*>(&u[(row0 + r)*UW_ + 3*E_ + g8]);
        }
    }

    float bl[16], qv[16], vv[16];
#pragma unroll
    for (int i=0;i<16;i++)
        bl[i] = bf2f(u[urow0 + (size_t)(t0+i)*UW_ + 2*E_]);
#pragma unroll
    for (int i=0;i<16;i++)
        qv[i] = bf2f(u[urow0 + (size_t)(t0+i)*UW_ + E_]);
#pragma unroll
    for (int i=0;i<16;i++)
        vv[i] = bf2f(u[urow0 + (size_t)(t0+i)*UW_]);

    float acc = 0.f;
#pragma unroll
    for (int i=0;i<16;i++){
        const float lg = bl[i];
        const float e  = __expf(-fabsf(lg));
        const float g  = fminf(lg, 0.f) - __logf(1.f + e);
        acc += g;
        bl[i] = acc;
    }
    tot[qd*128 + d] = acc;
    __syncthreads();
    const float s0 = tot[d], s1 = tot[128+d], s2 = tot[256+d], s3 = tot[384+d];
    const float off = (qd>0 ? s0 : 0.f) + (qd>1 ? s1 : 0.f) + (qd>2 ? s2 : 0.f);
    const float bcv = s0 + s1 + s2 + s3;
    const float ebc = __expf(bcv);
    if (threadIdx.x < 128) EBC[(size_t)bid*D_ + d] = ebc;

    unsigned kin_pk[8], v_pk[8];
    float prev = 0.f;
    const size_t obase = (size_t)bid*CHUNK*D_;
#pragma unroll
    for (int i=0;i<16;i++){
        const int t = t0 + i;
        const float Bl = bl[i];
        const float g  = Bl - prev;  prev = Bl;
        const float Bc = Bl + off;
        const float kk = 1.f - __expf(g);
        const float eB = __expf(Bc);
        const float q  = qv[i];
        const float es = __expf(-q);
        const float silu = q * __builtin_amdgcn_rcpf(1.f + es);
        const float qs  = silu * eB;
        const float kin = kk * __builtin_amdgcn_rcpf(eB);
        QSb [obase + (size_t)t*D_ + d] = f2bf_fast(qs);
        KINb[obase + (size_t)t*D_ + d] = f2bf_fast(kin);
        const unsigned kb = f2bf_fast(kin * ebc);
        const unsigned vb = f2bf_fast(vv[i]);
        if (i & 1){ kin_pk[i>>1] |= kb<<16; v_pk[i>>1] |= vb<<16; }
        else      { kin_pk[i>>1]  = kb;     v_pk[i>>1]  = vb;     }
    }
    const size_t tbase = (size_t)bid*D_*CHUNK + (size_t)d*CHUNK + t0;
#pragma unroll
    for (int j=0;j<2;j++){
        uint4 kq, vq;
        kq.x=kin_pk[4*j]; kq.y=kin_pk[4*j+1]; kq.z=kin_pk[4*j+2]; kq.w=kin_pk[4*j+3];
        vq.x=v_pk[4*j];   vq.y=v_pk[4*j+1];   vq.z=v_pk[4*j+2];   vq.w=v_pk[4*j+3];
        *reinterpret_cast<uint4*>(&Vtb[tbase + j*8]) = vq;       // global (for gla_output)
        const int g = qd*2 + j;                                  // 16B col-group in row d
        *reinterpret_cast<uint4*>(&Vt_l[d*64 + ((g ^ (d&7))<<3)]) = vq;
        *reinterpret_cast<uint4*>(&Kt_l[d*64 + ((g ^ (d&7))<<3)]) = kq;
    }
    __syncthreads();

    // ---- fused chunk-summary MFMA: 8 waves, each a 64x32 quadrant ----
    {
        const int w = threadIdx.x >> 6, lane = threadIdx.x & 63;
        const int l15 = lane & 15, l4 = lane >> 4;
        const int wr = (w >> 2) * 64, wc = (w & 3) * 32;
        f32x4 mac[4][2];
#pragma unroll
        for (int i=0;i<4;i++)
#pragma unroll
            for (int j=0;j<2;j++)
#pragma unroll
                for (int q=0;q<4;q++) mac[i][j][q]=0.f;
#pragma unroll
        for (int ks=0; ks<2; ks++){
            bf16x8 av[4], bv[2];
#pragma unroll
            for (int f=0; f<4; f++) av[f] = ldsfrag128(Vt_l, wr + f*16 + l15, ks*4 + l4);
#pragma unroll
            for (int g=0; g<2; g++) bv[g] = ldsfrag128(Kt_l, wc + g*16 + l15, ks*4 + l4);
#pragma unroll
            for (int f=0; f<4; f++)
#pragma unroll
                for (int g=0; g<2; g++)
                    mac[f][g] = __builtin_amdgcn_mfma_f32_16x16x32_bf16(
                        av[f], bv[g], mac[f][g], 0, 0, 0);
        }
        unsigned short* C = McTb + (size_t)bid*128*128;
#pragma unroll
        for (int f=0; f<4; f++)
#pragma unroll
            for (int g=0; g<2; g++)
#pragma unroll
                for (int j=0;j<4;j++)
                    C[(size_t)(wr + f*16 + l4*4 + j)*128 + wc + g*16 + l15] = f2bf(mac[f][g][j]);
    }
}

// ---------------------------------------------------------------------------
// Inter-chunk scan, vectorized x4.
// ---------------------------------------------------------------------------
__global__ __launch_bounds__(256) void gla_scan_chunks(
    const unsigned short* __restrict__ McTb, const float* __restrict__ EBC,
    unsigned short* __restrict__ Sb16)
{
    const int F4 = blockIdx.x*256 + threadIdx.x;   // < B*H*D*D/4 = 65536
    const int e4 = F4 << 2;
    const int bh = e4 >> 14;
    const int rem = e4 & 16383;
    const int d0 = rem & 127;
    float S0=0.f, S1=0.f, S2=0.f, S3=0.f;
    for (int c=0;c<NC_;c++){
        const size_t idx = (((size_t)bh*NC_ + c) << 14) + rem;
        const ushort4 m4 = *reinterpret_cast<const ushort4*>(&McTb[idx]);
        const float4 dec = *reinterpret_cast<const float4*>(
            &EBC[(((size_t)bh*NC_ + c) << 7) + d0]);
        ushort4 s4;
        s4.x = f2bf(S0); s4.y = f2bf(S1); s4.z = f2bf(S2); s4.w = f2bf(S3);
        *reinterpret_cast<ushort4*>(&Sb16[idx]) = s4;
        S0 = dec.x*S0 + bf2f(m4.x);
        S1 = dec.y*S1 + bf2f(m4.y);
        S2 = dec.z*S2 + bf2f(m4.z);
        S3 = dec.w*S3 + bf2f(m4.w);
    }
}

// ---------------------------------------------------------------------------
// Output (r11 proven): QS in LDS, KIN/Vt/S direct-from-global, G2b gate,
// bf16 Opre.
// ---------------------------------------------------------------------------
__global__ __launch_bounds__(256) void gla_output(
    const unsigned short* __restrict__ QSb,
    const unsigned short* __restrict__ KINb,
    const unsigned short* __restrict__ Vtb,
    const unsigned short* __restrict__ Sb,
    const unsigned short* __restrict__ G2b,
    unsigned short* __restrict__ Opre)
{
    __shared__ unsigned short QS_l[64*128];   // 16 KB
    __shared__ unsigned short A_l [64*64];    //  8 KB
    const int bid = blockIdx.x;
    const int c = bid % NC_;
    const int h = (bid / NC_) % H_;
    const int b = bid / (NC_*H_);
    const int tid = threadIdx.x;
    const int w = tid >> 6, lane = tid & 63;
    const int l15 = lane & 15, l4 = lane >> 4;

    const unsigned short* qb = QSb + (size_t)bid*64*128;
    const unsigned short* kb = KINb + (size_t)bid*64*128;
    const unsigned short* vb = Vtb + (size_t)bid*128*64;
    const unsigned short* sb = Sb  + (size_t)bid*128*128;

#pragma unroll
    for (int i=0;i<4;i++){
        const int r  = w*16 + i*4 + (lane>>4);
        const int gs = (lane&15) ^ (r&7);
        gload_lds16(qb + (size_t)r*128 + gs*8, &QS_l[(w*16+i*4)*128]);
    }
    uint4 kinr[4];
    {
        const int srow = w*16 + l15;
#pragma unroll
        for (int ks=0; ks<4; ks++)
            kinr[ks] = *reinterpret_cast<const uint4*>(kb + (size_t)srow*128 + (ks*4 + l4)*8);
    }
    __syncthreads();

    uint4 vtr[2][2], sr[2][4];
#pragma unroll
    for (int fe=0; fe<2; fe++){
        const int row = w*32 + fe*16 + l15;
#pragma unroll
        for (int ks=0; ks<2; ks++)
            vtr[fe][ks] = *reinterpret_cast<const uint4*>(vb + (size_t)row*64 + (ks*4 + l4)*8);
#pragma unroll
        for (int ks=0; ks<4; ks++)
            sr[fe][ks]  = *reinterpret_cast<const uint4*>(sb + (size_t)row*128 + (ks*4 + l4)*8);
    }

    f32x4 accA[4];
#pragma unroll
    for (int i=0;i<4;i++)
#pragma unroll
        for (int q=0;q<4;q++) accA[i][q]=0.f;
#pragma unroll
    for (int ks=0; ks<4; ks++){
        const bf16x8 bv = u4_to_bf(kinr[ks]);
#pragma unroll
        for (int ft=0; ft<4; ft++){
            const bf16x8 av = ldsfrag256(QS_l, ft*16 + l15, ks*4 + l4);
            accA[ft] = __builtin_amdgcn_mfma_f32_16x16x32_bf16(av, bv, accA[ft], 0,0,0);
        }
    }
#pragma unroll
    for (int ft=0; ft<4; ft++)
#pragma unroll
        for (int j=0;j<4;j++){
            const int t = ft*16 + l4*4 + j;
            const int s = w*16 + l15;
            const float vA = (t >= s) ? accA[ft][j] : 0.f;
            A_l[t*64 + (((s>>3) ^ (t&7))<<3) + (s&7)] = f2bf(vA);
        }
    __syncthreads();

    f32x4 acc[4][2];
#pragma unroll
    for (int i=0;i<4;i++)
#pragma unroll
        for (int j=0;j<2;j++)
#pragma unroll
            for (int q=0;q<4;q++) acc[i][j][q]=0.f;
#pragma unroll
    for (int ks=0; ks<2; ks++){
        const bf16x8 b0 = u4_to_bf(vtr[0][ks]);
        const bf16x8 b1 = u4_to_bf(vtr[1][ks]);
#pragma unroll
        for (int ft=0; ft<4; ft++){
            const bf16x8 av = ldsfrag128(A_l, ft*16 + l15, ks*4 + l4);
            acc[ft][0] = __builtin_amdgcn_mfma_f32_16x16x32_bf16(av, b0, acc[ft][0], 0,0,0);
            acc[ft][1] = __builtin_amdgcn_mfma_f32_16x16x32_bf16(av, b1, acc[ft][1], 0,0,0);
        }
    }
#pragma unroll
    for (int ks=0; ks<4; ks++){
        const bf16x8 b0 = u4_to_bf(sr[0][ks]);
        const bf16x8 b1 = u4_to_bf(sr[1][ks]);
#pragma unroll
        for (int ft=0; ft<4; ft++){
            const bf16x8 av = ldsfrag256(QS_l, ft*16 + l15, ks*4 + l4);
            acc[ft][0] = __builtin_amdgcn_mfma_f32_16x16x32_bf16(av, b0, acc[ft][0], 0,0,0);
            acc[ft][1] = __builtin_amdgcn_mfma_f32_16x16x32_bf16(av, b1, acc[ft][1], 0,0,0);
        }
    }
    const size_t rowbase = (size_t)b*N_ + (size_t)c*CHUNK;
#pragma unroll
    for (int ft=0; ft<4; ft++)
#pragma unroll
        for (int fe=0; fe<2; fe++)
#pragma unroll
            for (int j=0;j<4;j++){
                const int t = ft*16 + l4*4 + j;
                const int e = w*32 + fe*16 + l15;
                const size_t idx = (rowbase + t)*E_ + h*D_ + e;
                const float g = sigmoidf_(bf2f(G2b[idx]));
                Opre[idx] = f2bf(acc[ft][fe][j] * g);
            }
}

// ---------------------------------------------------------------------------
__global__ __launch_bounds__(256) void ln_bf16(
    const unsigned short* __restrict__ O, const float* __restrict__ lnw,
    unsigned short* __restrict__ Ob)
{
    const int row = blockIdx.x;
    const int tid = threadIdx.x;
    const size_t off = (size_t)row*E_ + tid*4;
    const ushort4 ov = *reinterpret_cast<const ushort4*>(&O[off]);
    float4 o;
    o.x = bf2f(ov.x); o.y = bf2f(ov.y); o.z = bf2f(ov.z); o.w = bf2f(ov.w);
    float s1 = o.x+o.y+o.z+o.w;
    float s2 = o.x*o.x + o.y*o.y + o.z*o.z + o.w*o.w;
#pragma unroll
    for (int sh=32; sh>0; sh>>=1){
        s1 += __shfl_down(s1, sh);
        s2 += __shfl_down(s2, sh);
    }
    __shared__ float r1[4], r2[4];
    const int wid = tid >> 6;
    if ((tid & 63)==0){ r1[wid]=s1; r2[wid]=s2; }
    __syncthreads();
    s1 = r1[0]+r1[1]+r1[2]+r1[3];
    s2 = r2[0]+r2[1]+r2[2]+r2[3];
    const float mean = s1 * (1.f/E_);
    const float var  = s2 * (1.f/E_) - mean*mean;
    const float rs   = rsqrtf(var + 1e-5f);
    const float4 w = *reinterpret_cast<const float4*>(&lnw[tid*4]);
    ushort4 r;
    r.x = f2bf((o.x-mean)*rs*w.x); r.y = f2bf((o.y-mean)*rs*w.y);
    r.z = f2bf((o.z-mean)*rs*w.z); r.w = f2bf((o.w-mean)*rs*w.w);
    *reinterpret_cast<ushort4*>(&Ob[off]) = r;
}

// ---------------------------------------------------------------------------
extern "C" void kernel_launch(void* const* d_in, const int* in_sizes, int n_in,
                              void* d_out, int out_size, void* d_ws, size_t ws_size,
                              hipStream_t stream)
{
    const float* x     = (const float*)d_in[0];
    const float* W_in  = (const float*)d_in[1];
    const float* W_out = (const float*)d_in[2];
    const float* W_g1  = (const float*)d_in[3];
    const float* W_g2  = (const float*)d_in[4];
    const float* lnw   = (const float*)d_in[5];
    float* out = (float*)d_out;
    char* ws = (char*)d_ws;

    // workspace layout (bytes); total 234,094,592 (< proven-safe 246 MB)
    unsigned short* ub2    = (unsigned short*)(ws);             //  54,525,952 [B,N,3328]
    unsigned short* QSb    = (unsigned short*)(ws + 54525952);  //  16,777,216
    unsigned short* KINb   = (unsigned short*)(ws + 71303168);  //  16,777,216
    unsigned short* Vtb    = (unsigned short*)(ws + 88080384);  //  16,777,216
    unsigned short* McTb   = (unsigned short*)(ws + 104857600); //  33,554,432
    unsigned short* Sb16   = (unsigned short*)(ws + 138412032); //  33,554,432
    float*          EBC    = (float*)(ws + 171966464);          //     524,288
    unsigned short* Opre   = (unsigned short*)(ws + 172490752); //  16,777,216
    unsigned short* ObF    = (unsigned short*)(ws + 189267968); //  16,777,216
    unsigned short* xb     = (unsigned short*)(ws + 206045184); //  16,777,216 (dead after step 1)
    unsigned short* G2b    = (unsigned short*)(ws + 206045184); //  16,777,216 overlay on dead xb
    unsigned short* Wcatb  = (unsigned short*)(ws + 222822400); //   6,815,744 [3328,1024]
    unsigned short* W_outb = (unsigned short*)(ws + 229638144); //   2,097,152
    unsigned short* W_g2b  = (unsigned short*)(ws + 231735296); //     262,144
    unsigned short* G1c    = (unsigned short*)(ws + 231997440); //   2,097,152 [8192,128]

    const int M = B_*N_;     // 8192
    dim3 blk(256);

    // 0) merged casts
    cast_all<<<2048, blk, 0, stream>>>(x, W_in, W_g1, W_out, W_g2,
                                       xb, Wcatb, W_outb, W_g2b);

    // 1) u2 = x @ [W_in; W_g1; pad]^T  — 8-phase 256^2
    gemm_8ph<true><<<dim3(UW_/256, M/256), dim3(512), 0, stream>>>(
        xb, Wcatb, ub2, M, UW_, E_, E_, UW_);
    // 2) prep (stride 3328) + G1 compaction + FUSED chunk-summary -> McTb
    gla_prep<<<dim3(B_*H_*NC_), dim3(512), 0, stream>>>(
        ub2, EBC, QSb, KINb, Vtb, McTb, G1c);
    // 3) G2 = G1c @ W_g2^T  (dense lda=128) — m97
    gemm_bf16<true><<<dim3(E_/128, M/128), blk, 0, stream>>>(
        G1c, W_g2b, G2b, M, E_, D_, D_);
    // 4) inter-chunk scan (vectorized x4)
    gla_scan_chunks<<<dim3((B_*H_*D_*D_)/1024), blk, 0, stream>>>(McTb, EBC, Sb16);
    // 5) per-chunk outputs + gate -> bf16 Opre
    gla_output<<<dim3(B_*H_*NC_), blk, 0, stream>>>(QSb, KINb, Vtb, Sb16, G2b, Opre);
    // 6) layernorm -> bf16
    ln_bf16<<<dim3(M), blk, 0, stream>>>(Opre, lnw, ObF);
    // 7) out = LN(o) @ W_out^T — m97
    gemm_bf16<false><<<dim3(E_/128, M/128), blk, 0, stream>>>(
        ObF, W_outb, out, M, E_, E_, E_);
}